// Round 4
// baseline (630.222 us; speedup 1.0000x reference)
//
#include <hip/hip_runtime.h>
#include <math.h>

static constexpr int N_ = 2048, NG_ = 128, E_ = 32768, P_ = 131072,
  D_ = 128, H_ = 4, L_ = 2, MPD_ = 5, EDI_ = 16, EDH_ = 64,
  IND_ = 64, OUTD_ = 64, FFN_ = 512;

// ---------------- degree counting ----------------
__global__ void k_deg(const int* __restrict__ ei, int* __restrict__ din, int* __restrict__ dou) {
  int e = blockIdx.x * blockDim.x + threadIdx.x;
  if (e < E_) {
    atomicAdd(&dou[ei[e]], 1);        // edge_index[0] = src -> out_deg
    atomicAdd(&din[ei[E_ + e]], 1);   // edge_index[1] = dst -> in_deg
  }
}

// ---------------- node input projection + centrality ----------------
__global__ void k_nodeproj(const float* __restrict__ x_in, const float* __restrict__ W,
                           const float* __restrict__ b, const float* __restrict__ z_in,
                           const float* __restrict__ z_out, const int* __restrict__ din,
                           const int* __restrict__ dou, float* __restrict__ x) {
  int n = blockIdx.x;
  int d = threadIdx.x;            // 128
  __shared__ float xs[IND_];
  if (d < IND_) xs[d] = x_in[n * IND_ + d];
  __syncthreads();
  float acc = b[d];
  for (int i = 0; i < IND_; ++i) acc += xs[i] * W[i * D_ + d];
  int di = min(din[n], 63), dz = min(dou[n], 63);
  acc += z_in[di * D_ + d] + z_out[dz * D_ + d];
  x[n * D_ + d] = acc;
}

// ---------------- edge input projection ----------------
__global__ void k_eproj(const float* __restrict__ ein, const float* __restrict__ W,
                        const float* __restrict__ b, float* __restrict__ ea) {
  int idx = blockIdx.x * blockDim.x + threadIdx.x;  // E*EDH
  int e = idx >> 6, c = idx & 63;
  const float* row = ein + e * EDI_;
  float acc = b[c];
  for (int i = 0; i < EDI_; ++i) acc += row[i] * W[i * EDH_ + c];
  ea[idx] = acc;
}

// ---------------- edot[l,h,m][e] = edge_vec[l,h,m,:] . ea[e,:] ----------------
__global__ void k_edot(const float* __restrict__ evec, const float* __restrict__ ea,
                       float* __restrict__ edot) {
  int e = blockIdx.x * blockDim.x + threadIdx.x;
  int s = blockIdx.y;  // (l*H+h)*MPD+m, 0..39
  __shared__ float evs[EDH_];
  if (threadIdx.x < EDH_) evs[threadIdx.x] = evec[s * EDH_ + threadIdx.x];
  __syncthreads();
  if (e < E_) {
    const float* row = ea + e * EDH_;
    float acc = 0.f;
    for (int i = 0; i < EDH_; ++i) acc += evs[i] * row[i];
    edot[s * E_ + e] = acc;
  }
}

// ---------------- per-layer bias scatter: bias[h][src][dst_local] ----------------
__global__ void k_scatter(const int* __restrict__ psrc, const int* __restrict__ pdst,
                          const int* __restrict__ pedg, const int* __restrict__ plen,
                          const float* __restrict__ bsp, const float* __restrict__ edot_l,
                          float* __restrict__ bias) {
  int idx = blockIdx.x * blockDim.x + threadIdx.x;  // P*H
  if (idx >= P_ * H_) return;
  int p = idx >> 2, h = idx & 3;
  int len = plen[p];
  int src = psrc[p];
  int dst = pdst[p] & (NG_ - 1);
  float acc = 0.f;
  for (int m = 0; m < MPD_; ++m)
    if (m < len) acc += edot_l[(h * MPD_ + m) * E_ + pedg[p * MPD_ + m]];
  float val = acc / (float)len + bsp[len - 1];
  bias[(h * N_ + src) * NG_ + dst] = val;
}

// ---------------- layernorm ----------------
__global__ void k_ln(const float* __restrict__ x, const float* __restrict__ g,
                     const float* __restrict__ b, float* __restrict__ out) {
  int n = blockIdx.x;
  int d = threadIdx.x;  // 128
  float v = x[n * D_ + d];
  __shared__ float red[D_];
  red[d] = v; __syncthreads();
  for (int s = 64; s > 0; s >>= 1) { if (d < s) red[d] += red[d + s]; __syncthreads(); }
  float mean = red[0] * (1.0f / D_);
  __syncthreads();
  float c = v - mean;
  red[d] = c * c; __syncthreads();
  for (int s = 64; s > 0; s >>= 1) { if (d < s) red[d] += red[d + s]; __syncthreads(); }
  float var = red[0] * (1.0f / D_);
  out[n * D_ + d] = c * rsqrtf(var + 1e-5f) * g[d] + b[d];
}

// ---------------- QKV projections (8-row tiled) ----------------
static constexpr int QKV_ROWS = 8;
__global__ void k_qkv(const float* __restrict__ xn,
                      const float* __restrict__ Wq, const float* __restrict__ bq,
                      const float* __restrict__ Wk, const float* __restrict__ bk,
                      const float* __restrict__ Wv, const float* __restrict__ bv,
                      float* __restrict__ q, float* __restrict__ k, float* __restrict__ v) {
  int rb = blockIdx.x;            // N/8
  int mh = blockIdx.y;            // 3*H
  int mat = mh >> 2, h = mh & 3;
  int e = threadIdx.x;            // 128
  const float* W  = (mat == 0 ? Wq : mat == 1 ? Wk : Wv) + h * D_ * D_;
  const float* bb = (mat == 0 ? bq : mat == 1 ? bk : bv) + h * D_;
  float* out      = (mat == 0 ? q  : mat == 1 ? k  : v)  + h * N_ * D_;
  __shared__ float xs[QKV_ROWS][D_];
  int n0 = rb * QKV_ROWS;
  for (int r = 0; r < QKV_ROWS; ++r) xs[r][e] = xn[(n0 + r) * D_ + e];
  __syncthreads();
  float acc[QKV_ROWS];
  float bvv = bb[e];
  for (int r = 0; r < QKV_ROWS; ++r) acc[r] = bvv;
  for (int d0 = 0; d0 < D_; ++d0) {
    float w = W[d0 * D_ + e];
    for (int r = 0; r < QKV_ROWS; ++r) acc[r] += xs[r][d0] * w;
  }
  for (int r = 0; r < QKV_ROWS; ++r) out[(n0 + r) * D_ + e] = acc[r];
}

// ---------------- block-diagonal attention, one (h,n) row per block ----------------
__global__ void k_attn(const float* __restrict__ q, const float* __restrict__ k,
                       const float* __restrict__ v, const float* __restrict__ bias,
                       float* __restrict__ o) {
  int h = blockIdx.x >> 11;       // /2048
  int n = blockIdx.x & (N_ - 1);
  int j = threadIdx.x;            // 128
  int g0 = (n >> 7) << 7;         // graph block start
  __shared__ float qs[D_];
  __shared__ float ps[NG_];
  __shared__ float red[NG_];
  qs[j] = q[(h * N_ + n) * D_ + j];
  __syncthreads();
  const float* krow = k + (size_t)(h * N_ + g0 + j) * D_;
  float s = 0.f;
  for (int d0 = 0; d0 < D_; ++d0) s += qs[d0] * krow[d0];
  s = s * 0.088388347648318447f /* 1/sqrt(128) */ + bias[(size_t)(h * N_ + n) * NG_ + j];
  red[j] = s; __syncthreads();
  for (int st = 64; st > 0; st >>= 1) { if (j < st) red[j] = fmaxf(red[j], red[j + st]); __syncthreads(); }
  float m = fmaxf(red[0], 0.0f);  // off-block entries are exactly 0 in the reference
  __syncthreads();
  float p = expf(s - m);
  ps[j] = p;
  red[j] = p; __syncthreads();
  for (int st = 64; st > 0; st >>= 1) { if (j < st) red[j] += red[j + st]; __syncthreads(); }
  float denom = red[0] + (float)(N_ - NG_) * expf(-m);  // 1920 off-block exp(0-m) terms
  float inv = 1.0f / denom;
  const float* vb = v + (size_t)(h * N_ + g0) * D_;
  float acc = 0.f;
  for (int jj = 0; jj < NG_; ++jj) acc += ps[jj] * vb[jj * D_ + j];
  o[(size_t)(h * N_ + n) * D_ + j] = acc * inv;
}

// ---------------- output projection of attention + residual ----------------
static constexpr int OP_ROWS = 8;
__global__ void k_oproj(const float* __restrict__ o, const float* __restrict__ Wo,
                        const float* __restrict__ bo, float* __restrict__ x) {
  int n0 = blockIdx.x * OP_ROWS;
  int d = threadIdx.x;  // 128
  __shared__ float os[OP_ROWS][H_ * D_];  // 16 KB
  for (int r = 0; r < OP_ROWS; ++r)
    for (int h = 0; h < H_; ++h)
      os[r][h * D_ + d] = o[(size_t)(h * N_ + n0 + r) * D_ + d];
  __syncthreads();
  float acc[OP_ROWS];
  float bb = bo[d];
  for (int r = 0; r < OP_ROWS; ++r) acc[r] = bb;
  for (int k0 = 0; k0 < H_ * D_; ++k0) {
    float w = Wo[k0 * D_ + d];
    for (int r = 0; r < OP_ROWS; ++r) acc[r] += os[r][k0] * w;
  }
  for (int r = 0; r < OP_ROWS; ++r) x[(n0 + r) * D_ + d] += acc[r];
}

// ---------------- FFN1 with exact GELU ----------------
static constexpr int F1_ROWS = 8;
__global__ void k_ffn1(const float* __restrict__ x2, const float* __restrict__ W1,
                       const float* __restrict__ b1, float* __restrict__ h1) {
  int n0 = blockIdx.x * F1_ROWS;
  int f = blockIdx.y * 256 + threadIdx.x;
  __shared__ float xs[F1_ROWS][D_];  // 4 KB
  for (int i = threadIdx.x; i < F1_ROWS * D_; i += 256)
    xs[i / D_][i % D_] = x2[(n0 + i / D_) * D_ + (i % D_)];
  __syncthreads();
  float acc[F1_ROWS];
  float bb = b1[f];
  for (int r = 0; r < F1_ROWS; ++r) acc[r] = bb;
  for (int d0 = 0; d0 < D_; ++d0) {
    float w = W1[d0 * FFN_ + f];
    for (int r = 0; r < F1_ROWS; ++r) acc[r] += xs[r][d0] * w;
  }
  for (int r = 0; r < F1_ROWS; ++r) {
    float u = acc[r];
    h1[(size_t)(n0 + r) * FFN_ + f] = 0.5f * u * (1.0f + erff(u * 0.70710678118654752440f));
  }
}

// ---------------- FFN2 + residual ----------------
__global__ void k_ffn2(const float* __restrict__ h1, const float* __restrict__ W2,
                       const float* __restrict__ b2, float* __restrict__ x) {
  int n0 = blockIdx.x * OP_ROWS;
  int d = threadIdx.x;  // 128
  __shared__ float hs[OP_ROWS][FFN_];  // 16 KB
  for (int r = 0; r < OP_ROWS; ++r)
    for (int i = d; i < FFN_; i += 128) hs[r][i] = h1[(size_t)(n0 + r) * FFN_ + i];
  __syncthreads();
  float acc[OP_ROWS];
  float bb = b2[d];
  for (int r = 0; r < OP_ROWS; ++r) acc[r] = bb;
  for (int k0 = 0; k0 < FFN_; ++k0) {
    float w = W2[k0 * D_ + d];
    for (int r = 0; r < OP_ROWS; ++r) acc[r] += hs[r][k0] * w;
  }
  for (int r = 0; r < OP_ROWS; ++r) x[(n0 + r) * D_ + d] += acc[r];
}

// ---------------- final output projection ----------------
__global__ void k_out(const float* __restrict__ x, const float* __restrict__ W,
                      const float* __restrict__ b, float* __restrict__ out) {
  int n = blockIdx.x;
  int c = threadIdx.x;  // 64
  __shared__ float xs[D_];
  xs[c] = x[n * D_ + c];
  xs[c + 64] = x[n * D_ + c + 64];
  __syncthreads();
  float acc = b[c];
  for (int d0 = 0; d0 < D_; ++d0) acc += xs[d0] * W[d0 * OUTD_ + c];
  out[n * OUTD_ + c] = acc;
}

extern "C" void kernel_launch(void* const* d_in, const int* in_sizes, int n_in,
                              void* d_out, int out_size, void* d_ws, size_t ws_size,
                              hipStream_t stream) {
  const float* x_in      = (const float*)d_in[0];
  const float* edge_attr = (const float*)d_in[1];
  const int*   edge_index= (const int*)  d_in[2];
  const int*   path_src  = (const int*)  d_in[3];
  const int*   path_dst  = (const int*)  d_in[4];
  const int*   path_edges= (const int*)  d_in[5];
  const int*   path_lens = (const int*)  d_in[6];
  // d_in[7] = ptr (implied by n>>7, graphs are fixed-size blocks of 128)
  const float* W_in  = (const float*)d_in[8];
  const float* b_in  = (const float*)d_in[9];
  const float* W_ein = (const float*)d_in[10];
  const float* b_ein = (const float*)d_in[11];
  const float* z_in  = (const float*)d_in[12];
  const float* z_out = (const float*)d_in[13];
  const float* b_sp  = (const float*)d_in[14];
  const float* ln1_g = (const float*)d_in[15];
  const float* ln1_b = (const float*)d_in[16];
  const float* Wq    = (const float*)d_in[17];
  const float* bq    = (const float*)d_in[18];
  const float* Wk    = (const float*)d_in[19];
  const float* bk    = (const float*)d_in[20];
  const float* Wv    = (const float*)d_in[21];
  const float* bv    = (const float*)d_in[22];
  const float* evec  = (const float*)d_in[23];
  const float* Wo    = (const float*)d_in[24];
  const float* bo    = (const float*)d_in[25];
  const float* ln2_g = (const float*)d_in[26];
  const float* ln2_b = (const float*)d_in[27];
  const float* W_f1  = (const float*)d_in[28];
  const float* b_f1  = (const float*)d_in[29];
  const float* W_f2  = (const float*)d_in[30];
  const float* b_f2  = (const float*)d_in[31];
  const float* W_out = (const float*)d_in[32];
  const float* b_out = (const float*)d_in[33];
  float* out = (float*)d_out;

  // workspace layout
  char* wp = (char*)d_ws;
  auto alloc = [&](size_t bytes) { void* p = wp; wp += (bytes + 255) & ~(size_t)255; return p; };
  int*   deg_in  = (int*)  alloc(N_ * 4);
  int*   deg_out = (int*)  alloc(N_ * 4);
  float* x    = (float*)alloc((size_t)N_ * D_ * 4);
  float* ea   = (float*)alloc((size_t)E_ * EDH_ * 4);
  float* edot = (float*)alloc((size_t)L_ * H_ * MPD_ * E_ * 4);
  float* bias = (float*)alloc((size_t)H_ * N_ * NG_ * 4);
  float* xn   = (float*)alloc((size_t)N_ * D_ * 4);
  float* q    = (float*)alloc((size_t)H_ * N_ * D_ * 4);
  float* k    = (float*)alloc((size_t)H_ * N_ * D_ * 4);
  float* v    = (float*)alloc((size_t)H_ * N_ * D_ * 4);
  float* o    = (float*)alloc((size_t)H_ * N_ * D_ * 4);
  float* x2   = (float*)alloc((size_t)N_ * D_ * 4);
  float* h1   = (float*)alloc((size_t)N_ * FFN_ * 4);

  // degrees
  hipMemsetAsync(deg_in, 0, 2 * N_ * 4, stream);  // deg_in & deg_out contiguous
  k_deg<<<E_ / 256, 256, 0, stream>>>(edge_index, deg_in, deg_out);
  // node projection + centrality
  k_nodeproj<<<N_, D_, 0, stream>>>(x_in, W_in, b_in, z_in, z_out, deg_in, deg_out, x);
  // edge projection
  k_eproj<<<(E_ * EDH_) / 256, 256, 0, stream>>>(edge_attr, W_ein, b_ein, ea);
  // edot for both layers
  {
    dim3 g(E_ / 256, L_ * H_ * MPD_);
    k_edot<<<g, 256, 0, stream>>>(evec, ea, edot);
  }

  for (int l = 0; l < L_; ++l) {
    // LN1
    k_ln<<<N_, D_, 0, stream>>>(x, ln1_g + l * D_, ln1_b + l * D_, xn);
    // QKV
    {
      dim3 g(N_ / QKV_ROWS, 3 * H_);
      k_qkv<<<g, D_, 0, stream>>>(xn,
          Wq + (size_t)l * H_ * D_ * D_, bq + (size_t)l * H_ * D_,
          Wk + (size_t)l * H_ * D_ * D_, bk + (size_t)l * H_ * D_,
          Wv + (size_t)l * H_ * D_ * D_, bv + (size_t)l * H_ * D_,
          q, k, v);
    }
    // bias scatter
    hipMemsetAsync(bias, 0, (size_t)H_ * N_ * NG_ * 4, stream);
    k_scatter<<<(P_ * H_) / 256, 256, 0, stream>>>(path_src, path_dst, path_edges, path_lens,
        b_sp, edot + (size_t)l * H_ * MPD_ * E_, bias);
    // attention
    k_attn<<<H_ * N_, NG_, 0, stream>>>(q, k, v, bias, o);
    // output proj + residual
    k_oproj<<<N_ / OP_ROWS, D_, 0, stream>>>(o, Wo + (size_t)l * H_ * D_ * D_, bo + l * D_, x);
    // LN2
    k_ln<<<N_, D_, 0, stream>>>(x, ln2_g + l * D_, ln2_b + l * D_, x2);
    // FFN
    {
      dim3 g(N_ / F1_ROWS, FFN_ / 256);
      k_ffn1<<<g, 256, 0, stream>>>(x2, W_f1 + (size_t)l * D_ * FFN_, b_f1 + l * FFN_, h1);
    }
    k_ffn2<<<N_ / OP_ROWS, D_, 0, stream>>>(h1, W_f2 + (size_t)l * FFN_ * D_, b_f2 + l * D_, x);
  }
  // final projection
  k_out<<<N_, OUTD_, 0, stream>>>(x, W_out, b_out, out);
}

// Round 10
// 488.438 us; speedup vs baseline: 1.2903x; 1.2903x over previous
//
#include <hip/hip_runtime.h>
#include <math.h>

static constexpr int N_ = 2048, NG_ = 128, E_ = 32768, P_ = 131072,
  D_ = 128, H_ = 4, L_ = 2, MPD_ = 5, EDI_ = 16, EDH_ = 64,
  IND_ = 64, OUTD_ = 64, FFN_ = 512;

// ---------------- degree counting ----------------
__global__ void k_deg(const int* __restrict__ ei, int* __restrict__ din, int* __restrict__ dou) {
  int e = blockIdx.x * blockDim.x + threadIdx.x;
  if (e < E_) {
    atomicAdd(&dou[ei[e]], 1);        // edge_index[0] = src -> out_deg
    atomicAdd(&din[ei[E_ + e]], 1);   // edge_index[1] = dst -> in_deg
  }
}

// ---------------- node input projection + centrality ----------------
__global__ void k_nodeproj(const float* __restrict__ x_in, const float* __restrict__ W,
                           const float* __restrict__ b, const float* __restrict__ z_in,
                           const float* __restrict__ z_out, const int* __restrict__ din,
                           const int* __restrict__ dou, float* __restrict__ x) {
  int n = blockIdx.x;
  int d = threadIdx.x;            // 128
  __shared__ float xs[IND_];
  if (d < IND_) xs[d] = x_in[n * IND_ + d];
  __syncthreads();
  float acc = b[d];
  for (int i = 0; i < IND_; ++i) acc += xs[i] * W[i * D_ + d];
  int di = min(din[n], 63), dz = min(dou[n], 63);
  acc += z_in[di * D_ + d] + z_out[dz * D_ + d];
  x[n * D_ + d] = acc;
}

// ---------------- edge input projection ----------------
__global__ void k_eproj(const float* __restrict__ ein, const float* __restrict__ W,
                        const float* __restrict__ b, float* __restrict__ ea) {
  int idx = blockIdx.x * blockDim.x + threadIdx.x;  // E*EDH
  int e = idx >> 6, c = idx & 63;
  const float* row = ein + e * EDI_;
  float acc = b[c];
  for (int i = 0; i < EDI_; ++i) acc += row[i] * W[i * EDH_ + c];
  ea[idx] = acc;
}

// ---------------- edot v2: block stages 64-edge ea tile + all 40 evec slices ----
// edot[s][e] = evec[s,:]  . ea[e,:]   (s = (l*H+h)*MPD+m, 40 slices)
static constexpr int ED_PAD = EDH_ + 4;   // odd 16B-slot stride -> conflict-free b128
__global__ __launch_bounds__(256)
void k_edot2(const float* __restrict__ evec, const float* __restrict__ ea,
             float* __restrict__ edot) {
  __shared__ float eas[64][ED_PAD];
  __shared__ float evs[40][ED_PAD];
  int t = threadIdx.x;
  int e0 = blockIdx.x * 64;
  // stage ea tile (coalesced float4)
  for (int i = t; i < 64 * (EDH_ / 4); i += 256) {
    int r = i >> 4, c = (i & 15) << 2;
    float4 v = *(const float4*)(ea + (size_t)(e0 + r) * EDH_ + c);
    *(float4*)&eas[r][c] = v;
  }
  // stage all evec slices (40*64 floats)
  for (int i = t; i < 40 * (EDH_ / 4); i += 256) {
    int r = i >> 4, c = (i & 15) << 2;
    float4 v = *(const float4*)(evec + (size_t)r * EDH_ + c);
    *(float4*)&evs[r][c] = v;
  }
  __syncthreads();
  int le = t & 63;        // local edge (lane)  -> coalesced writes
  int s0 = t >> 6;        // 0..3, wave-uniform -> evs reads broadcast
  float acc[10];
  for (int ss = 0; ss < 10; ++ss) acc[ss] = 0.f;
  for (int i = 0; i < EDH_; i += 4) {
    float4 a = *(const float4*)&eas[le][i];
    for (int ss = 0; ss < 10; ++ss) {
      float4 b = *(const float4*)&evs[s0 + ss * 4][i];
      acc[ss] += a.x * b.x + a.y * b.y + a.z * b.z + a.w * b.w;
    }
  }
  for (int ss = 0; ss < 10; ++ss)
    edot[(size_t)(s0 + ss * 4) * E_ + e0 + le] = acc[ss];
}

// ---------------- per-layer bias scatter: bias[h][src][dst_local] ----------------
__global__ void k_scatter(const int* __restrict__ psrc, const int* __restrict__ pdst,
                          const int* __restrict__ pedg, const int* __restrict__ plen,
                          const float* __restrict__ bsp, const float* __restrict__ edot_l,
                          float* __restrict__ bias) {
  int idx = blockIdx.x * blockDim.x + threadIdx.x;  // P*H
  if (idx >= P_ * H_) return;
  int p = idx >> 2, h = idx & 3;
  int len = plen[p];
  int src = psrc[p];
  int dst = pdst[p] & (NG_ - 1);
  float acc = 0.f;
  for (int m = 0; m < MPD_; ++m)
    if (m < len) acc += edot_l[(h * MPD_ + m) * E_ + pedg[p * MPD_ + m]];
  float val = acc / (float)len + bsp[len - 1];
  bias[(h * N_ + src) * NG_ + dst] = val;
}

// ---------------- layernorm ----------------
__global__ void k_ln(const float* __restrict__ x, const float* __restrict__ g,
                     const float* __restrict__ b, float* __restrict__ out) {
  int n = blockIdx.x;
  int d = threadIdx.x;  // 128
  float v = x[n * D_ + d];
  __shared__ float red[D_];
  red[d] = v; __syncthreads();
  for (int s = 64; s > 0; s >>= 1) { if (d < s) red[d] += red[d + s]; __syncthreads(); }
  float mean = red[0] * (1.0f / D_);
  __syncthreads();
  float c = v - mean;
  red[d] = c * c; __syncthreads();
  for (int s = 64; s > 0; s >>= 1) { if (d < s) red[d] += red[d + s]; __syncthreads(); }
  float var = red[0] * (1.0f / D_);
  out[n * D_ + d] = c * rsqrtf(var + 1e-5f) * g[d] + b[d];
}

// ---------------- QKV projections (8-row tiled, b128 LDS reads) ----------------
static constexpr int QKV_ROWS = 8;
__global__ void k_qkv(const float* __restrict__ xn,
                      const float* __restrict__ Wq, const float* __restrict__ bq,
                      const float* __restrict__ Wk, const float* __restrict__ bk,
                      const float* __restrict__ Wv, const float* __restrict__ bv,
                      float* __restrict__ q, float* __restrict__ k, float* __restrict__ v) {
  int rb = blockIdx.x;            // N/8
  int mh = blockIdx.y;            // 3*H
  int mat = mh >> 2, h = mh & 3;
  int e = threadIdx.x;            // 128
  const float* W  = (mat == 0 ? Wq : mat == 1 ? Wk : Wv) + h * D_ * D_;
  const float* bb = (mat == 0 ? bq : mat == 1 ? bk : bv) + h * D_;
  float* out      = (mat == 0 ? q  : mat == 1 ? k  : v)  + h * N_ * D_;
  __shared__ float xs[QKV_ROWS][D_];
  int n0 = rb * QKV_ROWS;
  for (int r = 0; r < QKV_ROWS; ++r) xs[r][e] = xn[(n0 + r) * D_ + e];
  __syncthreads();
  float acc[QKV_ROWS];
  float bvv = bb[e];
  for (int r = 0; r < QKV_ROWS; ++r) acc[r] = bvv;
  for (int d0 = 0; d0 < D_; d0 += 4) {
    float w0 = W[(d0 + 0) * D_ + e];
    float w1 = W[(d0 + 1) * D_ + e];
    float w2 = W[(d0 + 2) * D_ + e];
    float w3 = W[(d0 + 3) * D_ + e];
    for (int r = 0; r < QKV_ROWS; ++r) {
      float4 xv = *(const float4*)&xs[r][d0];   // b128 broadcast
      acc[r] += xv.x * w0 + xv.y * w1 + xv.z * w2 + xv.w * w3;
    }
  }
  for (int r = 0; r < QKV_ROWS; ++r) out[(n0 + r) * D_ + e] = acc[r];
}

// ---------------- block-diagonal attention v2 ----------------
__global__ __launch_bounds__(256, 2)
void k_attn2(const float* __restrict__ q, const float* __restrict__ k,
             const float* __restrict__ v, const float* __restrict__ bias,
             float* __restrict__ o) {
  int bx = blockIdx.x;            // 1024 = H * (N/8)
  int h  = bx >> 8;
  int n0 = (bx & 255) * 8;
  int g0 = n0 & ~(NG_ - 1);       // graph block start
  int t  = threadIdx.x;           // 256
  int j    = t & 127;             // key column / output dim
  int half = t >> 7;              // 0/1
  int r0   = half * 4;            // this thread's 4 query rows

  __shared__ float Ks[NG_][D_ + 1];   // +1 pad: conflict-free column reads
  __shared__ float Qs[8][D_];
  __shared__ float Ps[8][NG_];
  __shared__ float rinv[8];

  // stage K block (coalesced float4 global reads)
  const float* kbase = k + (size_t)(h * N_ + g0) * D_;
  for (int i = t; i < NG_ * D_ / 4; i += 256) {
    int r = i >> 5, c = (i & 31) << 2;
    float4 kv = *(const float4*)(kbase + r * D_ + c);
    Ks[r][c] = kv.x; Ks[r][c + 1] = kv.y; Ks[r][c + 2] = kv.z; Ks[r][c + 3] = kv.w;
  }
  // stage Q rows
  const float* qbase = q + (size_t)(h * N_ + n0) * D_;
  for (int i = t; i < 8 * D_; i += 256) Qs[i >> 7][i & 127] = qbase[i];
  __syncthreads();

  // S = Q.K^T/sqrt(D) + bias ; lane j = key col, 4 rows per thread
  const float* bb = bias + (size_t)(h * N_ + n0) * NG_;
  float s0 = 0.f, s1 = 0.f, s2 = 0.f, s3 = 0.f;
  for (int d0 = 0; d0 < D_; ++d0) {
    float kk = Ks[j][d0];               // conflict-free (pad)
    s0 += Qs[r0 + 0][d0] * kk;          // broadcast reads
    s1 += Qs[r0 + 1][d0] * kk;
    s2 += Qs[r0 + 2][d0] * kk;
    s3 += Qs[r0 + 3][d0] * kk;
  }
  const float sc = 0.088388347648318447f;  // 1/sqrt(128)
  Ps[r0 + 0][j] = s0 * sc + bb[(r0 + 0) * NG_ + j];
  Ps[r0 + 1][j] = s1 * sc + bb[(r0 + 1) * NG_ + j];
  Ps[r0 + 2][j] = s2 * sc + bb[(r0 + 2) * NG_ + j];
  Ps[r0 + 3][j] = s3 * sc + bb[(r0 + 3) * NG_ + j];
  __syncthreads();

  // softmax: 32-thread group per row (rows 0..7), off-block term included
  int rr = t >> 5, c0 = t & 31;
  float a0 = Ps[rr][c0], a1 = Ps[rr][c0 + 32], a2 = Ps[rr][c0 + 64], a3 = Ps[rr][c0 + 96];
  float lm = fmaxf(fmaxf(a0, a1), fmaxf(a2, a3));
  for (int off = 16; off > 0; off >>= 1) lm = fmaxf(lm, __shfl_xor(lm, off, 32));
  float m = fmaxf(lm, 0.0f);            // 1920 off-block logits are exactly 0
  float e0 = expf(a0 - m), e1 = expf(a1 - m), e2 = expf(a2 - m), e3 = expf(a3 - m);
  Ps[rr][c0] = e0; Ps[rr][c0 + 32] = e1; Ps[rr][c0 + 64] = e2; Ps[rr][c0 + 96] = e3;
  float ls = e0 + e1 + e2 + e3;
  for (int off = 16; off > 0; off >>= 1) ls += __shfl_xor(ls, off, 32);
  if (c0 == 0) rinv[rr] = 1.0f / (ls + (float)(N_ - NG_) * expf(-m));
  __syncthreads();

  // O = P.V ; lane j = output dim, V coalesced from global (L2-resident)
  const float* vbase = v + (size_t)(h * N_ + g0) * D_;
  float o0 = 0.f, o1 = 0.f, o2 = 0.f, o3 = 0.f;
  for (int jj = 0; jj < NG_; ++jj) {
    float vv = vbase[jj * D_ + j];
    float p0 = Ps[r0 + 0][jj], p1 = Ps[r0 + 1][jj], p2 = Ps[r0 + 2][jj], p3 = Ps[r0 + 3][jj];
    o0 += p0 * vv; o1 += p1 * vv; o2 += p2 * vv; o3 += p3 * vv;
  }
  float* ob = o + (size_t)(h * N_ + n0) * D_;
  ob[(r0 + 0) * D_ + j] = o0 * rinv[r0 + 0];
  ob[(r0 + 1) * D_ + j] = o1 * rinv[r0 + 1];
  ob[(r0 + 2) * D_ + j] = o2 * rinv[r0 + 2];
  ob[(r0 + 3) * D_ + j] = o3 * rinv[r0 + 3];
}

// ---------------- output projection of attention + residual ----------------
static constexpr int OP_ROWS = 8;
__global__ void k_oproj(const float* __restrict__ o, const float* __restrict__ Wo,
                        const float* __restrict__ bo, float* __restrict__ x) {
  int n0 = blockIdx.x * OP_ROWS;
  int d = threadIdx.x;  // 128
  __shared__ float os[OP_ROWS][H_ * D_];  // 16 KB
  for (int r = 0; r < OP_ROWS; ++r)
    for (int h = 0; h < H_; ++h)
      os[r][h * D_ + d] = o[(size_t)(h * N_ + n0 + r) * D_ + d];
  __syncthreads();
  float acc[OP_ROWS];
  float bb = bo[d];
  for (int r = 0; r < OP_ROWS; ++r) acc[r] = bb;
  for (int k0 = 0; k0 < H_ * D_; k0 += 4) {
    float w0 = Wo[(k0 + 0) * D_ + d];
    float w1 = Wo[(k0 + 1) * D_ + d];
    float w2 = Wo[(k0 + 2) * D_ + d];
    float w3 = Wo[(k0 + 3) * D_ + d];
    for (int r = 0; r < OP_ROWS; ++r) {
      float4 ov = *(const float4*)&os[r][k0];   // b128 broadcast
      acc[r] += ov.x * w0 + ov.y * w1 + ov.z * w2 + ov.w * w3;
    }
  }
  for (int r = 0; r < OP_ROWS; ++r) x[(n0 + r) * D_ + d] += acc[r];
}

// ---------------- FFN1 with exact GELU ----------------
static constexpr int F1_ROWS = 8;
__global__ void k_ffn1(const float* __restrict__ x2, const float* __restrict__ W1,
                       const float* __restrict__ b1, float* __restrict__ h1) {
  int n0 = blockIdx.x * F1_ROWS;
  int f = blockIdx.y * 256 + threadIdx.x;
  __shared__ float xs[F1_ROWS][D_];  // 4 KB
  for (int i = threadIdx.x; i < F1_ROWS * D_; i += 256)
    xs[i / D_][i % D_] = x2[(n0 + i / D_) * D_ + (i % D_)];
  __syncthreads();
  float acc[F1_ROWS];
  float bb = b1[f];
  for (int r = 0; r < F1_ROWS; ++r) acc[r] = bb;
  for (int d0 = 0; d0 < D_; d0 += 4) {
    float w0 = W1[(d0 + 0) * FFN_ + f];
    float w1 = W1[(d0 + 1) * FFN_ + f];
    float w2 = W1[(d0 + 2) * FFN_ + f];
    float w3 = W1[(d0 + 3) * FFN_ + f];
    for (int r = 0; r < F1_ROWS; ++r) {
      float4 xv = *(const float4*)&xs[r][d0];   // b128 broadcast
      acc[r] += xv.x * w0 + xv.y * w1 + xv.z * w2 + xv.w * w3;
    }
  }
  for (int r = 0; r < F1_ROWS; ++r) {
    float u = acc[r];
    h1[(size_t)(n0 + r) * FFN_ + f] = 0.5f * u * (1.0f + erff(u * 0.70710678118654752440f));
  }
}

// ---------------- FFN2 + residual ----------------
__global__ void k_ffn2(const float* __restrict__ h1, const float* __restrict__ W2,
                       const float* __restrict__ b2, float* __restrict__ x) {
  int n0 = blockIdx.x * OP_ROWS;
  int d = threadIdx.x;  // 128
  __shared__ float hs[OP_ROWS][FFN_];  // 16 KB
  for (int r = 0; r < OP_ROWS; ++r)
    for (int i = d; i < FFN_; i += 128) hs[r][i] = h1[(size_t)(n0 + r) * FFN_ + i];
  __syncthreads();
  float acc[OP_ROWS];
  float bb = b2[d];
  for (int r = 0; r < OP_ROWS; ++r) acc[r] = bb;
  for (int k0 = 0; k0 < FFN_; k0 += 4) {
    float w0 = W2[(k0 + 0) * D_ + d];
    float w1 = W2[(k0 + 1) * D_ + d];
    float w2 = W2[(k0 + 2) * D_ + d];
    float w3 = W2[(k0 + 3) * D_ + d];
    for (int r = 0; r < OP_ROWS; ++r) {
      float4 hv = *(const float4*)&hs[r][k0];   // b128 broadcast
      acc[r] += hv.x * w0 + hv.y * w1 + hv.z * w2 + hv.w * w3;
    }
  }
  for (int r = 0; r < OP_ROWS; ++r) x[(n0 + r) * D_ + d] += acc[r];
}

// ---------------- final output projection ----------------
__global__ void k_out(const float* __restrict__ x, const float* __restrict__ W,
                      const float* __restrict__ b, float* __restrict__ out) {
  int n = blockIdx.x;
  int c = threadIdx.x;  // 64
  __shared__ float xs[D_];
  xs[c] = x[n * D_ + c];
  xs[c + 64] = x[n * D_ + c + 64];
  __syncthreads();
  float acc = b[c];
  for (int d0 = 0; d0 < D_; ++d0) acc += xs[d0] * W[d0 * OUTD_ + c];
  out[n * OUTD_ + c] = acc;
}

extern "C" void kernel_launch(void* const* d_in, const int* in_sizes, int n_in,
                              void* d_out, int out_size, void* d_ws, size_t ws_size,
                              hipStream_t stream) {
  const float* x_in      = (const float*)d_in[0];
  const float* edge_attr = (const float*)d_in[1];
  const int*   edge_index= (const int*)  d_in[2];
  const int*   path_src  = (const int*)  d_in[3];
  const int*   path_dst  = (const int*)  d_in[4];
  const int*   path_edges= (const int*)  d_in[5];
  const int*   path_lens = (const int*)  d_in[6];
  // d_in[7] = ptr (implied by n>>7, graphs are fixed-size blocks of 128)
  const float* W_in  = (const float*)d_in[8];
  const float* b_in  = (const float*)d_in[9];
  const float* W_ein = (const float*)d_in[10];
  const float* b_ein = (const float*)d_in[11];
  const float* z_in  = (const float*)d_in[12];
  const float* z_out = (const float*)d_in[13];
  const float* b_sp  = (const float*)d_in[14];
  const float* ln1_g = (const float*)d_in[15];
  const float* ln1_b = (const float*)d_in[16];
  const float* Wq    = (const float*)d_in[17];
  const float* bq    = (const float*)d_in[18];
  const float* Wk    = (const float*)d_in[19];
  const float* bk    = (const float*)d_in[20];
  const float* Wv    = (const float*)d_in[21];
  const float* bv    = (const float*)d_in[22];
  const float* evec  = (const float*)d_in[23];
  const float* Wo    = (const float*)d_in[24];
  const float* bo    = (const float*)d_in[25];
  const float* ln2_g = (const float*)d_in[26];
  const float* ln2_b = (const float*)d_in[27];
  const float* W_f1  = (const float*)d_in[28];
  const float* b_f1  = (const float*)d_in[29];
  const float* W_f2  = (const float*)d_in[30];
  const float* b_f2  = (const float*)d_in[31];
  const float* W_out = (const float*)d_in[32];
  const float* b_out = (const float*)d_in[33];
  float* out = (float*)d_out;

  // workspace layout
  char* wp = (char*)d_ws;
  auto alloc = [&](size_t bytes) { void* p = wp; wp += (bytes + 255) & ~(size_t)255; return p; };
  int*   deg_in  = (int*)  alloc(N_ * 4);
  int*   deg_out = (int*)  alloc(N_ * 4);
  float* x    = (float*)alloc((size_t)N_ * D_ * 4);
  float* ea   = (float*)alloc((size_t)E_ * EDH_ * 4);
  float* edot = (float*)alloc((size_t)L_ * H_ * MPD_ * E_ * 4);
  float* bias = (float*)alloc((size_t)H_ * N_ * NG_ * 4);
  float* xn   = (float*)alloc((size_t)N_ * D_ * 4);
  float* q    = (float*)alloc((size_t)H_ * N_ * D_ * 4);
  float* k    = (float*)alloc((size_t)H_ * N_ * D_ * 4);
  float* v    = (float*)alloc((size_t)H_ * N_ * D_ * 4);
  float* o    = (float*)alloc((size_t)H_ * N_ * D_ * 4);
  float* x2   = (float*)alloc((size_t)N_ * D_ * 4);
  float* h1   = (float*)alloc((size_t)N_ * FFN_ * 4);

  // degrees
  hipMemsetAsync(deg_in, 0, 2 * N_ * 4, stream);  // deg_in & deg_out contiguous
  k_deg<<<E_ / 256, 256, 0, stream>>>(edge_index, deg_in, deg_out);
  // node projection + centrality
  k_nodeproj<<<N_, D_, 0, stream>>>(x_in, W_in, b_in, z_in, z_out, deg_in, deg_out, x);
  // edge projection
  k_eproj<<<(E_ * EDH_) / 256, 256, 0, stream>>>(edge_attr, W_ein, b_ein, ea);
  // edot for both layers (v2: LDS-staged, coalesced)
  k_edot2<<<E_ / 64, 256, 0, stream>>>(evec, ea, edot);

  for (int l = 0; l < L_; ++l) {
    // LN1
    k_ln<<<N_, D_, 0, stream>>>(x, ln1_g + l * D_, ln1_b + l * D_, xn);
    // QKV
    {
      dim3 g(N_ / QKV_ROWS, 3 * H_);
      k_qkv<<<g, D_, 0, stream>>>(xn,
          Wq + (size_t)l * H_ * D_ * D_, bq + (size_t)l * H_ * D_,
          Wk + (size_t)l * H_ * D_ * D_, bk + (size_t)l * H_ * D_,
          Wv + (size_t)l * H_ * D_ * D_, bv + (size_t)l * H_ * D_,
          q, k, v);
    }
    // bias scatter
    hipMemsetAsync(bias, 0, (size_t)H_ * N_ * NG_ * 4, stream);
    k_scatter<<<(P_ * H_) / 256, 256, 0, stream>>>(path_src, path_dst, path_edges, path_lens,
        b_sp, edot + (size_t)l * H_ * MPD_ * E_, bias);
    // attention (v2: LDS-staged K, coalesced)
    k_attn2<<<H_ * (N_ / 8), 256, 0, stream>>>(q, k, v, bias, o);
    // output proj + residual
    k_oproj<<<N_ / OP_ROWS, D_, 0, stream>>>(o, Wo + (size_t)l * H_ * D_ * D_, bo + l * D_, x);
    // LN2
    k_ln<<<N_, D_, 0, stream>>>(x, ln2_g + l * D_, ln2_b + l * D_, x2);
    // FFN
    {
      dim3 g(N_ / F1_ROWS, FFN_ / 256);
      k_ffn1<<<g, 256, 0, stream>>>(x2, W_f1 + (size_t)l * D_ * FFN_, b_f1 + l * FFN_, h1);
    }
    k_ffn2<<<N_ / OP_ROWS, D_, 0, stream>>>(h1, W_f2 + (size_t)l * FFN_ * D_, b_f2 + l * D_, x);
  }
  // final projection
  k_out<<<N_, OUTD_, 0, stream>>>(x, W_out, b_out, out);
}

// Round 11
// 395.828 us; speedup vs baseline: 1.5922x; 1.2340x over previous
//
#include <hip/hip_runtime.h>
#include <math.h>

static constexpr int N_ = 2048, NG_ = 128, E_ = 32768, P_ = 131072,
  D_ = 128, H_ = 4, L_ = 2, MPD_ = 5, EDI_ = 16, EDH_ = 64,
  IND_ = 64, OUTD_ = 64, FFN_ = 512;

// ---------------- degree counting ----------------
__global__ void k_deg(const int* __restrict__ ei, int* __restrict__ din, int* __restrict__ dou) {
  int e = blockIdx.x * blockDim.x + threadIdx.x;
  if (e < E_) {
    atomicAdd(&dou[ei[e]], 1);        // edge_index[0] = src -> out_deg
    atomicAdd(&din[ei[E_ + e]], 1);   // edge_index[1] = dst -> in_deg
  }
}

// ---------------- node input projection + centrality ----------------
__global__ void k_nodeproj(const float* __restrict__ x_in, const float* __restrict__ W,
                           const float* __restrict__ b, const float* __restrict__ z_in,
                           const float* __restrict__ z_out, const int* __restrict__ din,
                           const int* __restrict__ dou, float* __restrict__ x) {
  int n = blockIdx.x;
  int d = threadIdx.x;            // 128
  __shared__ float xs[IND_];
  if (d < IND_) xs[d] = x_in[n * IND_ + d];
  __syncthreads();
  float acc = b[d];
  for (int i = 0; i < IND_; ++i) acc += xs[i] * W[i * D_ + d];
  int di = min(din[n], 63), dz = min(dou[n], 63);
  acc += z_in[di * D_ + d] + z_out[dz * D_ + d];
  x[n * D_ + d] = acc;
}

// ---------------- edge input projection ----------------
__global__ void k_eproj(const float* __restrict__ ein, const float* __restrict__ W,
                        const float* __restrict__ b, float* __restrict__ ea) {
  int idx = blockIdx.x * blockDim.x + threadIdx.x;  // E*EDH
  int e = idx >> 6, c = idx & 63;
  const float* row = ein + e * EDI_;
  float acc = b[c];
  for (int i = 0; i < EDI_; ++i) acc += row[i] * W[i * EDH_ + c];
  ea[idx] = acc;
}

// ---------------- edot v2: block stages 64-edge ea tile + all 40 evec slices ----
// edot[s][e] = evec[s,:]  . ea[e,:]   (s = (l*H+h)*MPD+m, 40 slices)
static constexpr int ED_PAD = EDH_ + 4;   // odd 16B-slot stride -> conflict-free b128
__global__ __launch_bounds__(256)
void k_edot2(const float* __restrict__ evec, const float* __restrict__ ea,
             float* __restrict__ edot) {
  __shared__ float eas[64][ED_PAD];
  __shared__ float evs[40][ED_PAD];
  int t = threadIdx.x;
  int e0 = blockIdx.x * 64;
  // stage ea tile (coalesced float4)
  for (int i = t; i < 64 * (EDH_ / 4); i += 256) {
    int r = i >> 4, c = (i & 15) << 2;
    float4 v = *(const float4*)(ea + (size_t)(e0 + r) * EDH_ + c);
    *(float4*)&eas[r][c] = v;
  }
  // stage all evec slices (40*64 floats)
  for (int i = t; i < 40 * (EDH_ / 4); i += 256) {
    int r = i >> 4, c = (i & 15) << 2;
    float4 v = *(const float4*)(evec + (size_t)r * EDH_ + c);
    *(float4*)&evs[r][c] = v;
  }
  __syncthreads();
  int le = t & 63;        // local edge (lane)  -> coalesced writes
  int s0 = t >> 6;        // 0..3, wave-uniform -> evs reads broadcast
  float acc[10];
  for (int ss = 0; ss < 10; ++ss) acc[ss] = 0.f;
  for (int i = 0; i < EDH_; i += 4) {
    float4 a = *(const float4*)&eas[le][i];
    for (int ss = 0; ss < 10; ++ss) {
      float4 b = *(const float4*)&evs[s0 + ss * 4][i];
      acc[ss] += a.x * b.x + a.y * b.y + a.z * b.z + a.w * b.w;
    }
  }
  for (int ss = 0; ss < 10; ++ss)
    edot[(size_t)(s0 + ss * 4) * E_ + e0 + le] = acc[ss];
}

// ---------------- per-layer bias scatter: bias[h][src][dst_local] ----------------
__global__ void k_scatter(const int* __restrict__ psrc, const int* __restrict__ pdst,
                          const int* __restrict__ pedg, const int* __restrict__ plen,
                          const float* __restrict__ bsp, const float* __restrict__ edot_l,
                          float* __restrict__ bias) {
  int idx = blockIdx.x * blockDim.x + threadIdx.x;  // P*H
  if (idx >= P_ * H_) return;
  int p = idx >> 2, h = idx & 3;
  int len = plen[p];
  int src = psrc[p];
  int dst = pdst[p] & (NG_ - 1);
  float acc = 0.f;
  for (int m = 0; m < MPD_; ++m)
    if (m < len) acc += edot_l[(h * MPD_ + m) * E_ + pedg[p * MPD_ + m]];
  float val = acc / (float)len + bsp[len - 1];
  bias[(h * N_ + src) * NG_ + dst] = val;
}

// ---------------- layernorm ----------------
__global__ void k_ln(const float* __restrict__ x, const float* __restrict__ g,
                     const float* __restrict__ b, float* __restrict__ out) {
  int n = blockIdx.x;
  int d = threadIdx.x;  // 128
  float v = x[n * D_ + d];
  __shared__ float red[D_];
  red[d] = v; __syncthreads();
  for (int s = 64; s > 0; s >>= 1) { if (d < s) red[d] += red[d + s]; __syncthreads(); }
  float mean = red[0] * (1.0f / D_);
  __syncthreads();
  float c = v - mean;
  red[d] = c * c; __syncthreads();
  for (int s = 64; s > 0; s >>= 1) { if (d < s) red[d] += red[d + s]; __syncthreads(); }
  float var = red[0] * (1.0f / D_);
  out[n * D_ + d] = c * rsqrtf(var + 1e-5f) * g[d] + b[d];
}

// ---------------- QKV projections (8-row tiled, b128 LDS reads) ----------------
static constexpr int QKV_ROWS = 8;
__global__ void k_qkv(const float* __restrict__ xn,
                      const float* __restrict__ Wq, const float* __restrict__ bq,
                      const float* __restrict__ Wk, const float* __restrict__ bk,
                      const float* __restrict__ Wv, const float* __restrict__ bv,
                      float* __restrict__ q, float* __restrict__ k, float* __restrict__ v) {
  int rb = blockIdx.x;            // N/8
  int mh = blockIdx.y;            // 3*H
  int mat = mh >> 2, h = mh & 3;
  int e = threadIdx.x;            // 128
  const float* W  = (mat == 0 ? Wq : mat == 1 ? Wk : Wv) + h * D_ * D_;
  const float* bb = (mat == 0 ? bq : mat == 1 ? bk : bv) + h * D_;
  float* out      = (mat == 0 ? q  : mat == 1 ? k  : v)  + h * N_ * D_;
  __shared__ float xs[QKV_ROWS][D_];
  int n0 = rb * QKV_ROWS;
  for (int r = 0; r < QKV_ROWS; ++r) xs[r][e] = xn[(n0 + r) * D_ + e];
  __syncthreads();
  float acc[QKV_ROWS];
  float bvv = bb[e];
  for (int r = 0; r < QKV_ROWS; ++r) acc[r] = bvv;
  for (int d0 = 0; d0 < D_; d0 += 4) {
    float w0 = W[(d0 + 0) * D_ + e];
    float w1 = W[(d0 + 1) * D_ + e];
    float w2 = W[(d0 + 2) * D_ + e];
    float w3 = W[(d0 + 3) * D_ + e];
    for (int r = 0; r < QKV_ROWS; ++r) {
      float4 xv = *(const float4*)&xs[r][d0];   // b128 broadcast
      acc[r] += xv.x * w0 + xv.y * w1 + xv.z * w2 + xv.w * w3;
    }
  }
  for (int r = 0; r < QKV_ROWS; ++r) out[(n0 + r) * D_ + e] = acc[r];
}

// ---------------- block-diagonal attention v2 ----------------
__global__ __launch_bounds__(256, 2)
void k_attn2(const float* __restrict__ q, const float* __restrict__ k,
             const float* __restrict__ v, const float* __restrict__ bias,
             float* __restrict__ o) {
  int bx = blockIdx.x;            // 1024 = H * (N/8)
  int h  = bx >> 8;
  int n0 = (bx & 255) * 8;
  int g0 = n0 & ~(NG_ - 1);       // graph block start
  int t  = threadIdx.x;           // 256
  int j    = t & 127;             // key column / output dim
  int half = t >> 7;              // 0/1
  int r0   = half * 4;            // this thread's 4 query rows

  __shared__ float Ks[NG_][D_ + 1];   // +1 pad: conflict-free column reads
  __shared__ float Qs[8][D_];
  __shared__ float Ps[8][NG_];
  __shared__ float rinv[8];

  // stage K block (coalesced float4 global reads)
  const float* kbase = k + (size_t)(h * N_ + g0) * D_;
  for (int i = t; i < NG_ * D_ / 4; i += 256) {
    int r = i >> 5, c = (i & 31) << 2;
    float4 kv = *(const float4*)(kbase + r * D_ + c);
    Ks[r][c] = kv.x; Ks[r][c + 1] = kv.y; Ks[r][c + 2] = kv.z; Ks[r][c + 3] = kv.w;
  }
  // stage Q rows
  const float* qbase = q + (size_t)(h * N_ + n0) * D_;
  for (int i = t; i < 8 * D_; i += 256) Qs[i >> 7][i & 127] = qbase[i];
  __syncthreads();

  // S = Q.K^T/sqrt(D) + bias ; lane j = key col, 4 rows per thread
  const float* bb = bias + (size_t)(h * N_ + n0) * NG_;
  float s0 = 0.f, s1 = 0.f, s2 = 0.f, s3 = 0.f;
  for (int d0 = 0; d0 < D_; ++d0) {
    float kk = Ks[j][d0];               // conflict-free (pad)
    s0 += Qs[r0 + 0][d0] * kk;          // broadcast reads
    s1 += Qs[r0 + 1][d0] * kk;
    s2 += Qs[r0 + 2][d0] * kk;
    s3 += Qs[r0 + 3][d0] * kk;
  }
  const float sc = 0.088388347648318447f;  // 1/sqrt(128)
  Ps[r0 + 0][j] = s0 * sc + bb[(r0 + 0) * NG_ + j];
  Ps[r0 + 1][j] = s1 * sc + bb[(r0 + 1) * NG_ + j];
  Ps[r0 + 2][j] = s2 * sc + bb[(r0 + 2) * NG_ + j];
  Ps[r0 + 3][j] = s3 * sc + bb[(r0 + 3) * NG_ + j];
  __syncthreads();

  // softmax: 32-thread group per row (rows 0..7), off-block term included
  int rr = t >> 5, c0 = t & 31;
  float a0 = Ps[rr][c0], a1 = Ps[rr][c0 + 32], a2 = Ps[rr][c0 + 64], a3 = Ps[rr][c0 + 96];
  float lm = fmaxf(fmaxf(a0, a1), fmaxf(a2, a3));
  for (int off = 16; off > 0; off >>= 1) lm = fmaxf(lm, __shfl_xor(lm, off, 32));
  float m = fmaxf(lm, 0.0f);            // 1920 off-block logits are exactly 0
  float e0 = expf(a0 - m), e1 = expf(a1 - m), e2 = expf(a2 - m), e3 = expf(a3 - m);
  Ps[rr][c0] = e0; Ps[rr][c0 + 32] = e1; Ps[rr][c0 + 64] = e2; Ps[rr][c0 + 96] = e3;
  float ls = e0 + e1 + e2 + e3;
  for (int off = 16; off > 0; off >>= 1) ls += __shfl_xor(ls, off, 32);
  if (c0 == 0) rinv[rr] = 1.0f / (ls + (float)(N_ - NG_) * expf(-m));
  __syncthreads();

  // O = P.V ; lane j = output dim, V coalesced from global (L2-resident)
  const float* vbase = v + (size_t)(h * N_ + g0) * D_;
  float o0 = 0.f, o1 = 0.f, o2 = 0.f, o3 = 0.f;
  for (int jj = 0; jj < NG_; ++jj) {
    float vv = vbase[jj * D_ + j];
    float p0 = Ps[r0 + 0][jj], p1 = Ps[r0 + 1][jj], p2 = Ps[r0 + 2][jj], p3 = Ps[r0 + 3][jj];
    o0 += p0 * vv; o1 += p1 * vv; o2 += p2 * vv; o3 += p3 * vv;
  }
  float* ob = o + (size_t)(h * N_ + n0) * D_;
  ob[(r0 + 0) * D_ + j] = o0 * rinv[r0 + 0];
  ob[(r0 + 1) * D_ + j] = o1 * rinv[r0 + 1];
  ob[(r0 + 2) * D_ + j] = o2 * rinv[r0 + 2];
  ob[(r0 + 3) * D_ + j] = o3 * rinv[r0 + 3];
}

// ---------------- output projection + residual, split-K over heads ----------------
// grid (N/8, H); chunk h covers k in [h*128, h*128+128); atomicAdd partials into x.
static constexpr int OP_ROWS = 8;
__global__ __launch_bounds__(128)
void k_oproj(const float* __restrict__ o, const float* __restrict__ Wo,
             const float* __restrict__ bo, float* __restrict__ x) {
  int n0 = blockIdx.x * OP_ROWS;
  int h  = blockIdx.y;            // head = K-chunk
  int d = threadIdx.x;            // 128
  __shared__ float os[OP_ROWS][D_];  // 4 KB
  for (int r = 0; r < OP_ROWS; ++r)
    os[r][d] = o[(size_t)(h * N_ + n0 + r) * D_ + d];
  __syncthreads();
  float acc[OP_ROWS];
  float bb = (h == 0) ? bo[d] : 0.0f;   // bias added once (chunk 0)
  for (int r = 0; r < OP_ROWS; ++r) acc[r] = bb;
  const float* W = Wo + (size_t)h * D_ * D_;   // rows h*128..h*128+127
  for (int k0 = 0; k0 < D_; k0 += 4) {
    float w0 = W[(k0 + 0) * D_ + d];
    float w1 = W[(k0 + 1) * D_ + d];
    float w2 = W[(k0 + 2) * D_ + d];
    float w3 = W[(k0 + 3) * D_ + d];
    for (int r = 0; r < OP_ROWS; ++r) {
      float4 ov = *(const float4*)&os[r][k0];   // b128 broadcast
      acc[r] += ov.x * w0 + ov.y * w1 + ov.z * w2 + ov.w * w3;
    }
  }
  for (int r = 0; r < OP_ROWS; ++r)
    atomicAdd(&x[(size_t)(n0 + r) * D_ + d], acc[r]);
}

// ---------------- FFN1 with exact GELU ----------------
static constexpr int F1_ROWS = 8;
__global__ void k_ffn1(const float* __restrict__ x2, const float* __restrict__ W1,
                       const float* __restrict__ b1, float* __restrict__ h1) {
  int n0 = blockIdx.x * F1_ROWS;
  int f = blockIdx.y * 256 + threadIdx.x;
  __shared__ float xs[F1_ROWS][D_];  // 4 KB
  for (int i = threadIdx.x; i < F1_ROWS * D_; i += 256)
    xs[i / D_][i % D_] = x2[(n0 + i / D_) * D_ + (i % D_)];
  __syncthreads();
  float acc[F1_ROWS];
  float bb = b1[f];
  for (int r = 0; r < F1_ROWS; ++r) acc[r] = bb;
  for (int d0 = 0; d0 < D_; d0 += 4) {
    float w0 = W1[(d0 + 0) * FFN_ + f];
    float w1 = W1[(d0 + 1) * FFN_ + f];
    float w2 = W1[(d0 + 2) * FFN_ + f];
    float w3 = W1[(d0 + 3) * FFN_ + f];
    for (int r = 0; r < F1_ROWS; ++r) {
      float4 xv = *(const float4*)&xs[r][d0];   // b128 broadcast
      acc[r] += xv.x * w0 + xv.y * w1 + xv.z * w2 + xv.w * w3;
    }
  }
  for (int r = 0; r < F1_ROWS; ++r) {
    float u = acc[r];
    h1[(size_t)(n0 + r) * FFN_ + f] = 0.5f * u * (1.0f + erff(u * 0.70710678118654752440f));
  }
}

// ---------------- FFN2 + residual, split-K (4 chunks of 128) ----------------
// grid (N/8, 4); chunk c covers k in [c*128, c*128+128); atomicAdd into x.
__global__ __launch_bounds__(128)
void k_ffn2(const float* __restrict__ h1, const float* __restrict__ W2,
            const float* __restrict__ b2, float* __restrict__ x) {
  int n0 = blockIdx.x * OP_ROWS;
  int c  = blockIdx.y;            // K-chunk
  int d = threadIdx.x;            // 128
  int kb = c * 128;
  __shared__ float hs[OP_ROWS][128];  // 4 KB
  for (int r = 0; r < OP_ROWS; ++r)
    hs[r][d] = h1[(size_t)(n0 + r) * FFN_ + kb + d];
  __syncthreads();
  float acc[OP_ROWS];
  float bb = (c == 0) ? b2[d] : 0.0f;   // bias added once (chunk 0)
  for (int r = 0; r < OP_ROWS; ++r) acc[r] = bb;
  const float* W = W2 + (size_t)kb * D_;
  for (int k0 = 0; k0 < 128; k0 += 4) {
    float w0 = W[(k0 + 0) * D_ + d];
    float w1 = W[(k0 + 1) * D_ + d];
    float w2 = W[(k0 + 2) * D_ + d];
    float w3 = W[(k0 + 3) * D_ + d];
    for (int r = 0; r < OP_ROWS; ++r) {
      float4 hv = *(const float4*)&hs[r][k0];   // b128 broadcast
      acc[r] += hv.x * w0 + hv.y * w1 + hv.z * w2 + hv.w * w3;
    }
  }
  for (int r = 0; r < OP_ROWS; ++r)
    atomicAdd(&x[(size_t)(n0 + r) * D_ + d], acc[r]);
}

// ---------------- final output projection ----------------
__global__ void k_out(const float* __restrict__ x, const float* __restrict__ W,
                      const float* __restrict__ b, float* __restrict__ out) {
  int n = blockIdx.x;
  int c = threadIdx.x;  // 64
  __shared__ float xs[D_];
  xs[c] = x[n * D_ + c];
  xs[c + 64] = x[n * D_ + c + 64];
  __syncthreads();
  float acc = b[c];
  for (int d0 = 0; d0 < D_; ++d0) acc += xs[d0] * W[d0 * OUTD_ + c];
  out[n * OUTD_ + c] = acc;
}

extern "C" void kernel_launch(void* const* d_in, const int* in_sizes, int n_in,
                              void* d_out, int out_size, void* d_ws, size_t ws_size,
                              hipStream_t stream) {
  const float* x_in      = (const float*)d_in[0];
  const float* edge_attr = (const float*)d_in[1];
  const int*   edge_index= (const int*)  d_in[2];
  const int*   path_src  = (const int*)  d_in[3];
  const int*   path_dst  = (const int*)  d_in[4];
  const int*   path_edges= (const int*)  d_in[5];
  const int*   path_lens = (const int*)  d_in[6];
  // d_in[7] = ptr (implied by n>>7, graphs are fixed-size blocks of 128)
  const float* W_in  = (const float*)d_in[8];
  const float* b_in  = (const float*)d_in[9];
  const float* W_ein = (const float*)d_in[10];
  const float* b_ein = (const float*)d_in[11];
  const float* z_in  = (const float*)d_in[12];
  const float* z_out = (const float*)d_in[13];
  const float* b_sp  = (const float*)d_in[14];
  const float* ln1_g = (const float*)d_in[15];
  const float* ln1_b = (const float*)d_in[16];
  const float* Wq    = (const float*)d_in[17];
  const float* bq    = (const float*)d_in[18];
  const float* Wk    = (const float*)d_in[19];
  const float* bk    = (const float*)d_in[20];
  const float* Wv    = (const float*)d_in[21];
  const float* bv    = (const float*)d_in[22];
  const float* evec  = (const float*)d_in[23];
  const float* Wo    = (const float*)d_in[24];
  const float* bo    = (const float*)d_in[25];
  const float* ln2_g = (const float*)d_in[26];
  const float* ln2_b = (const float*)d_in[27];
  const float* W_f1  = (const float*)d_in[28];
  const float* b_f1  = (const float*)d_in[29];
  const float* W_f2  = (const float*)d_in[30];
  const float* b_f2  = (const float*)d_in[31];
  const float* W_out = (const float*)d_in[32];
  const float* b_out = (const float*)d_in[33];
  float* out = (float*)d_out;

  // workspace layout
  char* wp = (char*)d_ws;
  auto alloc = [&](size_t bytes) { void* p = wp; wp += (bytes + 255) & ~(size_t)255; return p; };
  int*   deg_in  = (int*)  alloc(N_ * 4);
  int*   deg_out = (int*)  alloc(N_ * 4);
  float* x    = (float*)alloc((size_t)N_ * D_ * 4);
  float* ea   = (float*)alloc((size_t)E_ * EDH_ * 4);
  float* edot = (float*)alloc((size_t)L_ * H_ * MPD_ * E_ * 4);
  float* bias = (float*)alloc((size_t)H_ * N_ * NG_ * 4);
  float* xn   = (float*)alloc((size_t)N_ * D_ * 4);
  float* q    = (float*)alloc((size_t)H_ * N_ * D_ * 4);
  float* k    = (float*)alloc((size_t)H_ * N_ * D_ * 4);
  float* v    = (float*)alloc((size_t)H_ * N_ * D_ * 4);
  float* o    = (float*)alloc((size_t)H_ * N_ * D_ * 4);
  float* x2   = (float*)alloc((size_t)N_ * D_ * 4);
  float* h1   = (float*)alloc((size_t)N_ * FFN_ * 4);

  // degrees
  hipMemsetAsync(deg_in, 0, 2 * N_ * 4, stream);  // deg_in & deg_out contiguous
  k_deg<<<E_ / 256, 256, 0, stream>>>(edge_index, deg_in, deg_out);
  // node projection + centrality
  k_nodeproj<<<N_, D_, 0, stream>>>(x_in, W_in, b_in, z_in, z_out, deg_in, deg_out, x);
  // edge projection
  k_eproj<<<(E_ * EDH_) / 256, 256, 0, stream>>>(edge_attr, W_ein, b_ein, ea);
  // edot for both layers (v2: LDS-staged, coalesced)
  k_edot2<<<E_ / 64, 256, 0, stream>>>(evec, ea, edot);

  for (int l = 0; l < L_; ++l) {
    // LN1
    k_ln<<<N_, D_, 0, stream>>>(x, ln1_g + l * D_, ln1_b + l * D_, xn);
    // QKV
    {
      dim3 g(N_ / QKV_ROWS, 3 * H_);
      k_qkv<<<g, D_, 0, stream>>>(xn,
          Wq + (size_t)l * H_ * D_ * D_, bq + (size_t)l * H_ * D_,
          Wk + (size_t)l * H_ * D_ * D_, bk + (size_t)l * H_ * D_,
          Wv + (size_t)l * H_ * D_ * D_, bv + (size_t)l * H_ * D_,
          q, k, v);
    }
    // bias scatter
    hipMemsetAsync(bias, 0, (size_t)H_ * N_ * NG_ * 4, stream);
    k_scatter<<<(P_ * H_) / 256, 256, 0, stream>>>(path_src, path_dst, path_edges, path_lens,
        b_sp, edot + (size_t)l * H_ * MPD_ * E_, bias);
    // attention (v2: LDS-staged K, coalesced)
    k_attn2<<<H_ * (N_ / 8), 256, 0, stream>>>(q, k, v, bias, o);
    // output proj + residual (split-K over heads, atomic)
    {
      dim3 g(N_ / OP_ROWS, H_);
      k_oproj<<<g, D_, 0, stream>>>(o, Wo + (size_t)l * H_ * D_ * D_, bo + l * D_, x);
    }
    // LN2
    k_ln<<<N_, D_, 0, stream>>>(x, ln2_g + l * D_, ln2_b + l * D_, x2);
    // FFN
    {
      dim3 g(N_ / F1_ROWS, FFN_ / 256);
      k_ffn1<<<g, 256, 0, stream>>>(x2, W_f1 + (size_t)l * D_ * FFN_, b_f1 + l * FFN_, h1);
    }
    {
      dim3 g(N_ / OP_ROWS, FFN_ / 128);
      k_ffn2<<<g, D_, 0, stream>>>(h1, W_f2 + (size_t)l * FFN_ * D_, b_f2 + l * D_, x);
    }
  }
  // final projection
  k_out<<<N_, OUTD_, 0, stream>>>(x, W_out, b_out, out);
}

// Round 16
// 389.180 us; speedup vs baseline: 1.6194x; 1.0171x over previous
//
#include <hip/hip_runtime.h>
#include <math.h>

static constexpr int N_ = 2048, NG_ = 128, E_ = 32768, P_ = 131072,
  D_ = 128, H_ = 4, L_ = 2, MPD_ = 5, EDI_ = 16, EDH_ = 64,
  IND_ = 64, OUTD_ = 64, FFN_ = 512;

// ---------------- degree counting ----------------
__global__ void k_deg(const int* __restrict__ ei, int* __restrict__ din, int* __restrict__ dou) {
  int e = blockIdx.x * blockDim.x + threadIdx.x;
  if (e < E_) {
    atomicAdd(&dou[ei[e]], 1);        // edge_index[0] = src -> out_deg
    atomicAdd(&din[ei[E_ + e]], 1);   // edge_index[1] = dst -> in_deg
  }
}

// ---------------- node input projection + centrality ----------------
__global__ void k_nodeproj(const float* __restrict__ x_in, const float* __restrict__ W,
                           const float* __restrict__ b, const float* __restrict__ z_in,
                           const float* __restrict__ z_out, const int* __restrict__ din,
                           const int* __restrict__ dou, float* __restrict__ x) {
  int n = blockIdx.x;
  int d = threadIdx.x;            // 128
  __shared__ float xs[IND_];
  if (d < IND_) xs[d] = x_in[n * IND_ + d];
  __syncthreads();
  float acc = b[d];
  for (int i = 0; i < IND_; ++i) acc += xs[i] * W[i * D_ + d];
  int di = min(din[n], 63), dz = min(dou[n], 63);
  acc += z_in[di * D_ + d] + z_out[dz * D_ + d];
  x[n * D_ + d] = acc;
}

// ---------------- edge input projection ----------------
__global__ void k_eproj(const float* __restrict__ ein, const float* __restrict__ W,
                        const float* __restrict__ b, float* __restrict__ ea) {
  int idx = blockIdx.x * blockDim.x + threadIdx.x;  // E*EDH
  int e = idx >> 6, c = idx & 63;
  const float* row = ein + e * EDI_;
  float acc = b[c];
  for (int i = 0; i < EDI_; ++i) acc += row[i] * W[i * EDH_ + c];
  ea[idx] = acc;
}

// ---------------- edot v2: block stages 64-edge ea tile + all 40 evec slices ----
static constexpr int ED_PAD = EDH_ + 4;   // odd 16B-slot stride -> conflict-free b128
__global__ __launch_bounds__(256)
void k_edot2(const float* __restrict__ evec, const float* __restrict__ ea,
             float* __restrict__ edot) {
  __shared__ float eas[64][ED_PAD];
  __shared__ float evs[40][ED_PAD];
  int t = threadIdx.x;
  int e0 = blockIdx.x * 64;
  for (int i = t; i < 64 * (EDH_ / 4); i += 256) {
    int r = i >> 4, c = (i & 15) << 2;
    float4 v = *(const float4*)(ea + (size_t)(e0 + r) * EDH_ + c);
    *(float4*)&eas[r][c] = v;
  }
  for (int i = t; i < 40 * (EDH_ / 4); i += 256) {
    int r = i >> 4, c = (i & 15) << 2;
    float4 v = *(const float4*)(evec + (size_t)r * EDH_ + c);
    *(float4*)&evs[r][c] = v;
  }
  __syncthreads();
  int le = t & 63;
  int s0 = t >> 6;
  float acc[10];
  for (int ss = 0; ss < 10; ++ss) acc[ss] = 0.f;
  for (int i = 0; i < EDH_; i += 4) {
    float4 a = *(const float4*)&eas[le][i];
    for (int ss = 0; ss < 10; ++ss) {
      float4 b = *(const float4*)&evs[s0 + ss * 4][i];
      acc[ss] += a.x * b.x + a.y * b.y + a.z * b.z + a.w * b.w;
    }
  }
  for (int ss = 0; ss < 10; ++ss)
    edot[(size_t)(s0 + ss * 4) * E_ + e0 + le] = acc[ss];
}

// ---------------- bias scatter v2: one thread per path, all 4 heads ----------------
__global__ void k_scatter(const int* __restrict__ psrc, const int* __restrict__ pdst,
                          const int* __restrict__ pedg, const int* __restrict__ plen,
                          const float* __restrict__ bsp, const float* __restrict__ edot_l,
                          float* __restrict__ bias) {
  int p = blockIdx.x * blockDim.x + threadIdx.x;
  if (p >= P_) return;
  int len = plen[p];
  int src = psrc[p];
  int dst = pdst[p] & (NG_ - 1);
  int ei[MPD_];
  for (int m = 0; m < MPD_; ++m) ei[m] = pedg[p * MPD_ + m];
  float bs = bsp[len - 1];
  for (int h = 0; h < H_; ++h) {
    float acc = 0.f;
    for (int m = 0; m < MPD_; ++m)
      if (m < len) acc += edot_l[(size_t)(h * MPD_ + m) * E_ + ei[m]];
    bias[(size_t)(h * N_ + src) * NG_ + dst] = acc / (float)len + bs;
  }
}

// ---------------- QKV projections with fused LN1 (8-row tiled, b128 LDS reads) ----
static constexpr int QKV_ROWS = 8;
__global__ void k_qkv(const float* __restrict__ x,
                      const float* __restrict__ lg, const float* __restrict__ lb,
                      const float* __restrict__ Wq, const float* __restrict__ bq,
                      const float* __restrict__ Wk, const float* __restrict__ bk,
                      const float* __restrict__ Wv, const float* __restrict__ bv,
                      float* __restrict__ q, float* __restrict__ k, float* __restrict__ v) {
  int rb = blockIdx.x;            // N/8
  int mh = blockIdx.y;            // 3*H
  int mat = mh >> 2, h = mh & 3;
  int e = threadIdx.x;            // 128
  const float* W  = (mat == 0 ? Wq : mat == 1 ? Wk : Wv) + h * D_ * D_;
  const float* bb = (mat == 0 ? bq : mat == 1 ? bk : bv) + h * D_;
  float* out      = (mat == 0 ? q  : mat == 1 ? k  : v)  + h * N_ * D_;
  __shared__ float xs[QKV_ROWS][D_];
  __shared__ float mu[QKV_ROWS], rstd[QKV_ROWS];
  int n0 = rb * QKV_ROWS;
  for (int r = 0; r < QKV_ROWS; ++r) xs[r][e] = x[(n0 + r) * D_ + e];
  __syncthreads();
  // inline LN1: 16-lane group per row
  {
    int rr = e >> 4, l16 = e & 15;
    float s = 0.f;
    for (int i = 0; i < 8; ++i) s += xs[rr][l16 + 16 * i];
    for (int m = 1; m < 16; m <<= 1) s += __shfl_xor(s, m, 16);
    float mean = s * (1.0f / D_);
    float vv = 0.f;
    for (int i = 0; i < 8; ++i) { float c = xs[rr][l16 + 16 * i] - mean; vv += c * c; }
    for (int m = 1; m < 16; m <<= 1) vv += __shfl_xor(vv, m, 16);
    if (l16 == 0) { mu[rr] = mean; rstd[rr] = rsqrtf(vv * (1.0f / D_) + 1e-5f); }
  }
  __syncthreads();
  float gg = lg[e], gb = lb[e];
  for (int r = 0; r < QKV_ROWS; ++r) xs[r][e] = (xs[r][e] - mu[r]) * rstd[r] * gg + gb;
  __syncthreads();
  float acc[QKV_ROWS];
  float bvv = bb[e];
  for (int r = 0; r < QKV_ROWS; ++r) acc[r] = bvv;
  for (int d0 = 0; d0 < D_; d0 += 4) {
    float w0 = W[(d0 + 0) * D_ + e];
    float w1 = W[(d0 + 1) * D_ + e];
    float w2 = W[(d0 + 2) * D_ + e];
    float w3 = W[(d0 + 3) * D_ + e];
    for (int r = 0; r < QKV_ROWS; ++r) {
      float4 xv = *(const float4*)&xs[r][d0];   // b128 broadcast
      acc[r] += xv.x * w0 + xv.y * w1 + xv.z * w2 + xv.w * w3;
    }
  }
  for (int r = 0; r < QKV_ROWS; ++r) out[(n0 + r) * D_ + e] = acc[r];
}

// ---------------- block-diagonal attention v2 ----------------
__global__ __launch_bounds__(256, 2)
void k_attn2(const float* __restrict__ q, const float* __restrict__ k,
             const float* __restrict__ v, const float* __restrict__ bias,
             float* __restrict__ o) {
  int bx = blockIdx.x;            // 1024 = H * (N/8)
  int h  = bx >> 8;
  int n0 = (bx & 255) * 8;
  int g0 = n0 & ~(NG_ - 1);       // graph block start
  int t  = threadIdx.x;           // 256
  int j    = t & 127;             // key column / output dim
  int half = t >> 7;              // 0/1
  int r0   = half * 4;            // this thread's 4 query rows

  __shared__ float Ks[NG_][D_ + 1];   // +1 pad: conflict-free column reads
  __shared__ float Qs[8][D_];
  __shared__ float Ps[8][NG_];
  __shared__ float rinv[8];

  const float* kbase = k + (size_t)(h * N_ + g0) * D_;
  for (int i = t; i < NG_ * D_ / 4; i += 256) {
    int r = i >> 5, c = (i & 31) << 2;
    float4 kv = *(const float4*)(kbase + r * D_ + c);
    Ks[r][c] = kv.x; Ks[r][c + 1] = kv.y; Ks[r][c + 2] = kv.z; Ks[r][c + 3] = kv.w;
  }
  const float* qbase = q + (size_t)(h * N_ + n0) * D_;
  for (int i = t; i < 8 * D_; i += 256) Qs[i >> 7][i & 127] = qbase[i];
  __syncthreads();

  const float* bb = bias + (size_t)(h * N_ + n0) * NG_;
  float s0 = 0.f, s1 = 0.f, s2 = 0.f, s3 = 0.f;
  for (int d0 = 0; d0 < D_; ++d0) {
    float kk = Ks[j][d0];               // conflict-free (pad)
    s0 += Qs[r0 + 0][d0] * kk;          // broadcast reads
    s1 += Qs[r0 + 1][d0] * kk;
    s2 += Qs[r0 + 2][d0] * kk;
    s3 += Qs[r0 + 3][d0] * kk;
  }
  const float sc = 0.088388347648318447f;  // 1/sqrt(128)
  Ps[r0 + 0][j] = s0 * sc + bb[(r0 + 0) * NG_ + j];
  Ps[r0 + 1][j] = s1 * sc + bb[(r0 + 1) * NG_ + j];
  Ps[r0 + 2][j] = s2 * sc + bb[(r0 + 2) * NG_ + j];
  Ps[r0 + 3][j] = s3 * sc + bb[(r0 + 3) * NG_ + j];
  __syncthreads();

  int rr = t >> 5, c0 = t & 31;
  float a0 = Ps[rr][c0], a1 = Ps[rr][c0 + 32], a2 = Ps[rr][c0 + 64], a3 = Ps[rr][c0 + 96];
  float lm = fmaxf(fmaxf(a0, a1), fmaxf(a2, a3));
  for (int off = 16; off > 0; off >>= 1) lm = fmaxf(lm, __shfl_xor(lm, off, 32));
  float m = fmaxf(lm, 0.0f);            // 1920 off-block logits are exactly 0
  float e0 = expf(a0 - m), e1 = expf(a1 - m), e2 = expf(a2 - m), e3 = expf(a3 - m);
  Ps[rr][c0] = e0; Ps[rr][c0 + 32] = e1; Ps[rr][c0 + 64] = e2; Ps[rr][c0 + 96] = e3;
  float ls = e0 + e1 + e2 + e3;
  for (int off = 16; off > 0; off >>= 1) ls += __shfl_xor(ls, off, 32);
  if (c0 == 0) rinv[rr] = 1.0f / (ls + (float)(N_ - NG_) * expf(-m));
  __syncthreads();

  const float* vbase = v + (size_t)(h * N_ + g0) * D_;
  float o0 = 0.f, o1 = 0.f, o2 = 0.f, o3 = 0.f;
  for (int jj = 0; jj < NG_; ++jj) {
    float vv = vbase[jj * D_ + j];
    float p0 = Ps[r0 + 0][jj], p1 = Ps[r0 + 1][jj], p2 = Ps[r0 + 2][jj], p3 = Ps[r0 + 3][jj];
    o0 += p0 * vv; o1 += p1 * vv; o2 += p2 * vv; o3 += p3 * vv;
  }
  float* ob = o + (size_t)(h * N_ + n0) * D_;
  ob[(r0 + 0) * D_ + j] = o0 * rinv[r0 + 0];
  ob[(r0 + 1) * D_ + j] = o1 * rinv[r0 + 1];
  ob[(r0 + 2) * D_ + j] = o2 * rinv[r0 + 2];
  ob[(r0 + 3) * D_ + j] = o3 * rinv[r0 + 3];
}

// ---------------- output projection + residual, split-K over heads ----------------
static constexpr int OP_ROWS = 8;
__global__ __launch_bounds__(128)
void k_oproj(const float* __restrict__ o, const float* __restrict__ Wo,
             const float* __restrict__ bo, float* __restrict__ x) {
  int n0 = blockIdx.x * OP_ROWS;
  int h  = blockIdx.y;            // head = K-chunk
  int d = threadIdx.x;            // 128
  __shared__ float os[OP_ROWS][D_];  // 4 KB
  for (int r = 0; r < OP_ROWS; ++r)
    os[r][d] = o[(size_t)(h * N_ + n0 + r) * D_ + d];
  __syncthreads();
  float acc[OP_ROWS];
  float bb = (h == 0) ? bo[d] : 0.0f;   // bias added once (chunk 0)
  for (int r = 0; r < OP_ROWS; ++r) acc[r] = bb;
  const float* W = Wo + (size_t)h * D_ * D_;
  for (int k0 = 0; k0 < D_; k0 += 4) {
    float w0 = W[(k0 + 0) * D_ + d];
    float w1 = W[(k0 + 1) * D_ + d];
    float w2 = W[(k0 + 2) * D_ + d];
    float w3 = W[(k0 + 3) * D_ + d];
    for (int r = 0; r < OP_ROWS; ++r) {
      float4 ov = *(const float4*)&os[r][k0];   // b128 broadcast
      acc[r] += ov.x * w0 + ov.y * w1 + ov.z * w2 + ov.w * w3;
    }
  }
  for (int r = 0; r < OP_ROWS; ++r)
    atomicAdd(&x[(size_t)(n0 + r) * D_ + d], acc[r]);
}

// ---------------- FFN1 with fused LN2 + exact GELU ----------------
static constexpr int F1_ROWS = 8;
__global__ void k_ffn1(const float* __restrict__ x,
                       const float* __restrict__ lg, const float* __restrict__ lb,
                       const float* __restrict__ W1, const float* __restrict__ bf1,
                       float* __restrict__ h1) {
  int n0 = blockIdx.x * F1_ROWS;
  int f = blockIdx.y * 256 + threadIdx.x;
  int t = threadIdx.x;
  __shared__ float xs[F1_ROWS][D_];  // 4 KB
  __shared__ float mu[F1_ROWS], rstd[F1_ROWS];
  for (int i = t; i < F1_ROWS * D_; i += 256)
    xs[i >> 7][i & 127] = x[(size_t)(n0 + (i >> 7)) * D_ + (i & 127)];
  __syncthreads();
  // inline LN2: 32-lane group per row
  {
    int rr = t >> 5, l32 = t & 31;
    float s = 0.f;
    for (int i = 0; i < 4; ++i) s += xs[rr][l32 + 32 * i];
    for (int m = 1; m < 32; m <<= 1) s += __shfl_xor(s, m, 32);
    float mean = s * (1.0f / D_);
    float vv = 0.f;
    for (int i = 0; i < 4; ++i) { float c = xs[rr][l32 + 32 * i] - mean; vv += c * c; }
    for (int m = 1; m < 32; m <<= 1) vv += __shfl_xor(vv, m, 32);
    if (l32 == 0) { mu[rr] = mean; rstd[rr] = rsqrtf(vv * (1.0f / D_) + 1e-5f); }
  }
  __syncthreads();
  for (int i = t; i < F1_ROWS * D_; i += 256) {
    int r = i >> 7, d = i & 127;
    xs[r][d] = (xs[r][d] - mu[r]) * rstd[r] * lg[d] + lb[d];
  }
  __syncthreads();
  float acc[F1_ROWS];
  float bb = bf1[f];
  for (int r = 0; r < F1_ROWS; ++r) acc[r] = bb;
  for (int d0 = 0; d0 < D_; d0 += 4) {
    float w0 = W1[(d0 + 0) * FFN_ + f];
    float w1 = W1[(d0 + 1) * FFN_ + f];
    float w2 = W1[(d0 + 2) * FFN_ + f];
    float w3 = W1[(d0 + 3) * FFN_ + f];
    for (int r = 0; r < F1_ROWS; ++r) {
      float4 xv = *(const float4*)&xs[r][d0];   // b128 broadcast
      acc[r] += xv.x * w0 + xv.y * w1 + xv.z * w2 + xv.w * w3;
    }
  }
  for (int r = 0; r < F1_ROWS; ++r) {
    float u = acc[r];
    h1[(size_t)(n0 + r) * FFN_ + f] = 0.5f * u * (1.0f + erff(u * 0.70710678118654752440f));
  }
}

// ---------------- FFN2 + residual, split-K (4 chunks of 128) ----------------
__global__ __launch_bounds__(128)
void k_ffn2(const float* __restrict__ h1, const float* __restrict__ W2,
            const float* __restrict__ b2, float* __restrict__ x) {
  int n0 = blockIdx.x * OP_ROWS;
  int c  = blockIdx.y;            // K-chunk
  int d = threadIdx.x;            // 128
  int kb = c * 128;
  __shared__ float hs[OP_ROWS][128];  // 4 KB
  for (int r = 0; r < OP_ROWS; ++r)
    hs[r][d] = h1[(size_t)(n0 + r) * FFN_ + kb + d];
  __syncthreads();
  float acc[OP_ROWS];
  float bb = (c == 0) ? b2[d] : 0.0f;   // bias added once (chunk 0)
  for (int r = 0; r < OP_ROWS; ++r) acc[r] = bb;
  const float* W = W2 + (size_t)kb * D_;
  for (int k0 = 0; k0 < 128; k0 += 4) {
    float w0 = W[(k0 + 0) * D_ + d];
    float w1 = W[(k0 + 1) * D_ + d];
    float w2 = W[(k0 + 2) * D_ + d];
    float w3 = W[(k0 + 3) * D_ + d];
    for (int r = 0; r < OP_ROWS; ++r) {
      float4 hv = *(const float4*)&hs[r][k0];   // b128 broadcast
      acc[r] += hv.x * w0 + hv.y * w1 + hv.z * w2 + hv.w * w3;
    }
  }
  for (int r = 0; r < OP_ROWS; ++r)
    atomicAdd(&x[(size_t)(n0 + r) * D_ + d], acc[r]);
}

// ---------------- final output projection ----------------
__global__ void k_out(const float* __restrict__ x, const float* __restrict__ W,
                      const float* __restrict__ b, float* __restrict__ out) {
  int n = blockIdx.x;
  int c = threadIdx.x;  // 64
  __shared__ float xs[D_];
  xs[c] = x[n * D_ + c];
  xs[c + 64] = x[n * D_ + c + 64];
  __syncthreads();
  float acc = b[c];
  for (int d0 = 0; d0 < D_; ++d0) acc += xs[d0] * W[d0 * OUTD_ + c];
  out[n * OUTD_ + c] = acc;
}

extern "C" void kernel_launch(void* const* d_in, const int* in_sizes, int n_in,
                              void* d_out, int out_size, void* d_ws, size_t ws_size,
                              hipStream_t stream) {
  const float* x_in      = (const float*)d_in[0];
  const float* edge_attr = (const float*)d_in[1];
  const int*   edge_index= (const int*)  d_in[2];
  const int*   path_src  = (const int*)  d_in[3];
  const int*   path_dst  = (const int*)  d_in[4];
  const int*   path_edges= (const int*)  d_in[5];
  const int*   path_lens = (const int*)  d_in[6];
  // d_in[7] = ptr (implied by n>>7, graphs are fixed-size blocks of 128)
  const float* W_in  = (const float*)d_in[8];
  const float* b_in  = (const float*)d_in[9];
  const float* W_ein = (const float*)d_in[10];
  const float* b_ein = (const float*)d_in[11];
  const float* z_in  = (const float*)d_in[12];
  const float* z_out = (const float*)d_in[13];
  const float* b_sp  = (const float*)d_in[14];
  const float* ln1_g = (const float*)d_in[15];
  const float* ln1_b = (const float*)d_in[16];
  const float* Wq    = (const float*)d_in[17];
  const float* bq    = (const float*)d_in[18];
  const float* Wk    = (const float*)d_in[19];
  const float* bk    = (const float*)d_in[20];
  const float* Wv    = (const float*)d_in[21];
  const float* bv    = (const float*)d_in[22];
  const float* evec  = (const float*)d_in[23];
  const float* Wo    = (const float*)d_in[24];
  const float* bo    = (const float*)d_in[25];
  const float* ln2_g = (const float*)d_in[26];
  const float* ln2_b = (const float*)d_in[27];
  const float* W_f1  = (const float*)d_in[28];
  const float* b_f1  = (const float*)d_in[29];
  const float* W_f2  = (const float*)d_in[30];
  const float* b_f2  = (const float*)d_in[31];
  const float* W_out = (const float*)d_in[32];
  const float* b_out = (const float*)d_in[33];
  float* out = (float*)d_out;

  // workspace layout
  char* wp = (char*)d_ws;
  auto alloc = [&](size_t bytes) { void* p = wp; wp += (bytes + 255) & ~(size_t)255; return p; };
  int*   deg_in  = (int*)  alloc(N_ * 4);
  int*   deg_out = (int*)  alloc(N_ * 4);
  float* x    = (float*)alloc((size_t)N_ * D_ * 4);
  float* ea   = (float*)alloc((size_t)E_ * EDH_ * 4);
  float* edot = (float*)alloc((size_t)L_ * H_ * MPD_ * E_ * 4);
  float* bias = (float*)alloc((size_t)H_ * N_ * NG_ * 4);
  float* q    = (float*)alloc((size_t)H_ * N_ * D_ * 4);
  float* k    = (float*)alloc((size_t)H_ * N_ * D_ * 4);
  float* v    = (float*)alloc((size_t)H_ * N_ * D_ * 4);
  float* o    = (float*)alloc((size_t)H_ * N_ * D_ * 4);
  float* h1   = (float*)alloc((size_t)N_ * FFN_ * 4);

  // degrees
  hipMemsetAsync(deg_in, 0, 2 * N_ * 4, stream);  // deg_in & deg_out contiguous
  k_deg<<<E_ / 256, 256, 0, stream>>>(edge_index, deg_in, deg_out);
  // node projection + centrality
  k_nodeproj<<<N_, D_, 0, stream>>>(x_in, W_in, b_in, z_in, z_out, deg_in, deg_out, x);
  // edge projection
  k_eproj<<<(E_ * EDH_) / 256, 256, 0, stream>>>(edge_attr, W_ein, b_ein, ea);
  // edot for both layers
  k_edot2<<<E_ / 64, 256, 0, stream>>>(evec, ea, edot);

  for (int l = 0; l < L_; ++l) {
    // QKV with fused LN1
    {
      dim3 g(N_ / QKV_ROWS, 3 * H_);
      k_qkv<<<g, D_, 0, stream>>>(x, ln1_g + l * D_, ln1_b + l * D_,
          Wq + (size_t)l * H_ * D_ * D_, bq + (size_t)l * H_ * D_,
          Wk + (size_t)l * H_ * D_ * D_, bk + (size_t)l * H_ * D_,
          Wv + (size_t)l * H_ * D_ * D_, bv + (size_t)l * H_ * D_,
          q, k, v);
    }
    // bias scatter (v2: per-path, all heads)
    hipMemsetAsync(bias, 0, (size_t)H_ * N_ * NG_ * 4, stream);
    k_scatter<<<P_ / 256, 256, 0, stream>>>(path_src, path_dst, path_edges, path_lens,
        b_sp, edot + (size_t)l * H_ * MPD_ * E_, bias);
    // attention
    k_attn2<<<H_ * (N_ / 8), 256, 0, stream>>>(q, k, v, bias, o);
    // output proj + residual (split-K over heads, atomic)
    {
      dim3 g(N_ / OP_ROWS, H_);
      k_oproj<<<g, D_, 0, stream>>>(o, Wo + (size_t)l * H_ * D_ * D_, bo + l * D_, x);
    }
    // FFN1 with fused LN2
    {
      dim3 g(N_ / F1_ROWS, FFN_ / 256);
      k_ffn1<<<g, 256, 0, stream>>>(x, ln2_g + l * D_, ln2_b + l * D_,
          W_f1 + (size_t)l * D_ * FFN_, b_f1 + l * FFN_, h1);
    }
    // FFN2 (split-K, atomic residual)
    {
      dim3 g(N_ / OP_ROWS, FFN_ / 128);
      k_ffn2<<<g, D_, 0, stream>>>(h1, W_f2 + (size_t)l * FFN_ * D_, b_f2 + l * D_, x);
    }
  }
  // final projection
  k_out<<<N_, OUTD_, 0, stream>>>(x, W_out, b_out, out);
}